// Round 8
// baseline (126.724 us; speedup 1.0000x reference)
//
#include <hip/hip_runtime.h>

// Conv4d implicit GEMM, v8.
// wprep: weights f32 -> bf16 in 32x32x16-fragment order:
//        Wg[off][rt 0..1][ks 0..1][kq 0..1][lane][8]; co = rt*32 + (l&31),
//        ci = ks*32 + kq*16 + 8*(l>>5) + e.
// sprep: unchanged: half-slabs S[(b,w',x')][ks][rem][32 ci], granule g at g^((rem>>1)&3).
// main:  block = (b,w,x), 512 thr / 8 waves = 4 sp-groups x 2 SUB-groups.
//        Both sub-groups read the SAME half-slab each tick (subs 0-4 / 5-8, parity-
//        alternating) -> 2-slot ring (41.5KB), 2 blocks/CU, 16 waves/CU = 4/SIMD.
//        MFMA v_mfma_f32_32x32x16_bf16 (A row=l&31, k=8*(l>>5)+e; C/D row=(r&3)+8*(r>>2)
//        +4*(l>>5), col=l&31 [m74/m101]). Pair-sum of sub-group partials via LDS.

typedef __attribute__((ext_vector_type(8))) short bf16x8;
typedef __attribute__((ext_vector_type(4))) float f32x4;
typedef __attribute__((ext_vector_type(16))) float f32x16;
typedef __attribute__((ext_vector_type(8))) unsigned short ushort8;
typedef unsigned short u16;
typedef unsigned int u32;

#define S_OFF_BYTES 663552u          // Wg = 81*4096 u16
#define WS_NEEDED   27537408u        // + 648 slabs * 41472 B

__device__ __forceinline__ u16 f2bf(float f) {
    u32 u = __float_as_uint(f);
    u += 0x7FFFu + ((u >> 16) & 1u);   // RNE
    return (u16)(u >> 16);
}

// ---------------- pre-pass 1: weights (32x32 fragment order) ----------------
__global__ __launch_bounds__(256) void wprep(const float* __restrict__ ker, u16* __restrict__ wg) {
    const int gg = blockIdx.x * 256 + threadIdx.x;     // 0..41471
    const int l = gg & 63, kq = (gg >> 6) & 1, ks = (gg >> 7) & 1, rt = (gg >> 8) & 1, off = gg >> 9;
    const int co  = rt * 32 + (l & 31);
    const int ci0 = ks * 32 + kq * 16 + 8 * (l >> 5);
    const float* p = ker + (size_t)off * 4096 + co;
    ushort8 v;
#pragma unroll
    for (int e = 0; e < 8; ++e) v[e] = f2bf(p[(size_t)(ci0 + e) * 64]);
    *(ushort8*)(wg + (size_t)gg * 8) = v;
}

// ---------------- pre-pass 2: input half-slabs (granule-swizzled) ----------------
__global__ __launch_bounds__(256) void sprep(const float* __restrict__ in, u16* __restrict__ s) {
    __shared__ u16 L[64 * 330];                        // [ci][rem padded]
    const int blk = blockIdx.x;                        // 648 = 2*18*18
    const int b = blk / 324, wx = blk - b * 324;
    const float* src = in + (size_t)b * 6718464 + (wx / 18) * 5832 + (wx % 18) * 324;
    const int t = threadIdx.x;
    for (int i = t; i < 5184; i += 256) {              // 64 ci * 81 float4
        const int ci = i / 81, j = i - ci * 81;
        float4 v = *(const float4*)(src + (size_t)ci * 104976 + j * 4);
        u32* q = (u32*)&L[ci * 330 + j * 4];
        q[0] = f2bf(v.x) | ((u32)f2bf(v.y) << 16);
        q[1] = f2bf(v.z) | ((u32)f2bf(v.w) << 16);
    }
    __syncthreads();
    u16* dst = s + (size_t)blk * 20736;                // [ks][rem][32 swizzled]
    for (int i = t; i < 2592; i += 256) {              // 2 ks * 324 rem * 4 granules
        const int ks = i / 1296, r4 = i - ks * 1296;
        const int rem = r4 >> 2, g = r4 & 3;
        ushort8 v;
#pragma unroll
        for (int e = 0; e < 8; ++e) v[e] = L[(ks * 32 + g * 8 + e) * 330 + rem];
        const int gp = g ^ ((rem >> 1) & 3);           // involution granule swizzle
        *(ushort8*)(dst + ks * 10368 + rem * 32 + gp * 8) = v;
    }
}

// ---------------- main-kernel inner compute ----------------
template<int S0, int NS>
__device__ __forceinline__ void compute_range(const u16* __restrict__ wo,   // +kwx*9*4096 + ksh*1024
                                              const u16* __restrict__ Tb,
                                              f32x16 (&acc)[2][2],
                                              int l, int yb, int zb, int lhi)
{
    bf16x8 aA[2][2], bB[2][2];
    auto lda = [&](bf16x8 (&dst)[2], int sub, int kq) {
#pragma unroll
        for (int rt = 0; rt < 2; ++rt)
            dst[rt] = *(const bf16x8*)(wo + (size_t)sub * 4096 + rt * 2048 + kq * 512 + l * 8);
    };
    auto ldb = [&](bf16x8 (&dst)[2], int sub, int kq) {
        const int ky = sub / 3, kz = sub - ky * 3;
#pragma unroll
        for (int ct = 0; ct < 2; ++ct) {
            const int rem = (yb + 2 * ct + ky) * 18 + zb + kz;
            dst[ct] = *(const bf16x8*)&Tb[rem * 32 + (((kq * 2 + lhi) ^ ((rem >> 1) & 3)) << 3)];
        }
    };
    lda(aA[0], S0, 0);
    ldb(bB[0], S0, 0);
#pragma unroll
    for (int n = 0; n < NS * 2; ++n) {                 // iter n: sub = S0 + n/2, kq = n&1
        const int cur = n & 1;
        if (n + 1 < NS * 2) {
            lda(aA[cur ^ 1], S0 + (n + 1) / 2, (n + 1) & 1);
            ldb(bB[cur ^ 1], S0 + (n + 1) / 2, (n + 1) & 1);
        }
        __builtin_amdgcn_s_setprio(1);
#pragma unroll
        for (int rt = 0; rt < 2; ++rt)
#pragma unroll
            for (int ct = 0; ct < 2; ++ct)
                acc[rt][ct] = __builtin_amdgcn_mfma_f32_32x32x16_bf16(
                    aA[cur][rt], bB[cur][ct], acc[rt][ct], 0, 0, 0);
        __builtin_amdgcn_s_setprio(0);
    }
}

// ---------------- main ----------------
__global__ __launch_bounds__(512, 4)
void conv4d_main(const u16* __restrict__ wg, const u16* __restrict__ s, float* __restrict__ out) {
    __shared__ u16 R[2][324 * 32];                     // 2-slot half-slab ring, 41472 B

    // bijective XCD swizzle (512 % 8 == 0)
    const int bid = blockIdx.x;
    const int bs  = (bid & 7) * 64 + (bid >> 3);
    const int b   = bs >> 8;
    const int w   = (bs >> 4) & 15;
    const int x   = bs & 15;

    const int tid = threadIdx.x, wv = tid >> 6, l = tid & 63;
    const int p   = wv >> 2;           // sub-group (0: subs 0-4 at ks0; 1: complement)
    const int g   = wv & 3;            // sp-group: y-rows 4g..4g+3
    const int lhi = l >> 5;
    const int yb  = 4 * g + ((l >> 4) & 1);
    const int zb  = l & 15;

    f32x16 acc[2][2];
#pragma unroll
    for (int i = 0; i < 2; ++i)
#pragma unroll
        for (int j = 0; j < 2; ++j)
#pragma unroll
            for (int e = 0; e < 16; ++e) acc[i][j][e] = 0.f;

    const u16* sb = s + (size_t)(b * 324 + w * 18 + x) * 20736;

    // half-slab h: kwx = h>>1, ks-half = h&1
#define STAGE_H(h, bufi)                                                             \
    do {                                                                             \
        const int kwx_ = (h) >> 1, ksh_ = (h) & 1;                                   \
        const int kw_ = kwx_ / 3, kx_ = kwx_ - kw_ * 3;                              \
        const u16* src_ = sb + (size_t)(kw_ * 18 + kx_) * 20736 + ksh_ * 10368;      \
        for (int i_ = tid; i_ < 1296; i_ += 512)                                     \
            __builtin_amdgcn_global_load_lds(                                        \
                (const __attribute__((address_space(1))) u32*)(src_ + i_ * 8),       \
                (__attribute__((address_space(3))) u32*)&R[bufi][i_ * 8], 16, 0, 0); \
    } while (0)

    STAGE_H(0, 0);
    __syncthreads();

#pragma unroll 2
    for (int t = 0; t < 18; ++t) {
        if (t + 1 < 18) STAGE_H(t + 1, (t + 1) & 1);   // prefetch next half-slab

        const int kwx = t >> 1, ksh = t & 1;
        const u16* wo = wg + (size_t)(kwx * 9) * 4096 + ksh * 1024;
        const u16* Tb = R[t & 1];

        if ((p ^ ksh) == 0) compute_range<0, 5>(wo, Tb, acc, l, yb, zb, lhi);
        else                compute_range<5, 4>(wo, Tb, acc, l, yb, zb, lhi);

        __syncthreads();                               // drains stage vmcnt; slot reuse safe
    }
#undef STAGE_H

    // epilogue: pair-sum sub-group partials via LDS (two rounds of 2 sp-groups, 32KB)
    float* rb = (float*)&R[0][0];
    float* ob = out + (size_t)b * 4194304 + (size_t)w * 4096 + (size_t)x * 256;
#pragma unroll
    for (int gsel = 0; gsel < 2; ++gsel) {
        if (p == 1 && (g >> 1) == gsel) {
#pragma unroll
            for (int rt = 0; rt < 2; ++rt)
#pragma unroll
                for (int ct = 0; ct < 2; ++ct)
#pragma unroll
                    for (int r = 0; r < 16; ++r)
                        rb[(g & 1) * 4096 + (rt * 2 + ct) * 1024 + r * 64 + l] = acc[rt][ct][r];
        }
        __syncthreads();
        if (p == 0 && (g >> 1) == gsel) {
#pragma unroll
            for (int rt = 0; rt < 2; ++rt)
#pragma unroll
                for (int ct = 0; ct < 2; ++ct) {
                    const int y = 4 * g + 2 * ct + ((l >> 4) & 1);
#pragma unroll
                    for (int r = 0; r < 16; ++r) {
                        const float v = rb[(g & 1) * 4096 + (rt * 2 + ct) * 1024 + r * 64 + l]
                                        + acc[rt][ct][r];
                        const int co = rt * 32 + (r & 3) + 8 * (r >> 2) + 4 * lhi;
                        ob[(size_t)co * 65536 + y * 16 + zb] = v;
                    }
                }
        }
        __syncthreads();
    }
}

// ---------------- fallback (round-1 kernel, used if ws too small) ----------------
__global__ __launch_bounds__(512, 2)
void conv4d_mfma(const float* __restrict__ in, const float* __restrict__ ker,
                 float* __restrict__ out) {
    __shared__ unsigned short T[18 * 18 * 64];
    __shared__ unsigned short Wt[2][64 * 64];
    const int bx = blockIdx.x;
    const int b = bx >> 8, wsp = (bx >> 4) & 15, x = bx & 15;
    const int t = threadIdx.x, wv = t >> 6, l = t & 63;
    const int lg = l >> 4, ll = l & 15;
    const float* inb = in + (size_t)b * 6718464 + wsp * 5832 + x * 324;
    f32x4 acc[4][2];
#pragma unroll
    for (int i = 0; i < 4; ++i)
#pragma unroll
        for (int j = 0; j < 2; ++j) acc[i][j] = (f32x4){0.f, 0.f, 0.f, 0.f};
#pragma unroll
    for (int f0 = 0; f0 < 4096; f0 += 512) {
        const int f = f0 + t, ci = f >> 6, co = f & 63;
        Wt[0][co * 64 + ((((ci >> 3) ^ (co & 7)) << 3) | (ci & 7))] = f2bf(ker[f]);
    }
    for (int off = 0; off < 81; ++off) {
        const int sub = off % 9;
        if (sub == 0) {
            const int kw = off / 27, kx = (off / 9) % 3;
            const float* p = inb + kw * 5832 + kx * 324;
            for (int f = t; f < 18 * 18 * 64; f += 512) {
                const int ci = f / 324, rem = f - ci * 324, zp = rem % 18;
                T[rem * 64 + ((((ci >> 3) ^ (zp & 7)) << 3) | (ci & 7))] =
                    f2bf(p[(size_t)ci * 104976 + rem]);
            }
        }
        if (off + 1 < 81) {
            const float* p = ker + (off + 1) * 4096;
            unsigned short* wb = Wt[(off + 1) & 1];
#pragma unroll
            for (int f0 = 0; f0 < 4096; f0 += 512) {
                const int f = f0 + t, ci = f >> 6, co = f & 63;
                wb[co * 64 + ((((ci >> 3) ^ (co & 7)) << 3) | (ci & 7))] = f2bf(p[f]);
            }
        }
        if (sub == 0) __syncthreads();
        const int ky = sub / 3, kz = sub - ky * 3;
        const int zp = ll + kz, zs = zp & 7;
#pragma unroll
        for (int ks = 0; ks < 2; ++ks) {
            bf16x8 af[4];
#pragma unroll
            for (int rt = 0; rt < 4; ++rt)
                af[rt] = *(const bf16x8*)&Wt[off & 1][(rt * 16 + ll) * 64 + (((lg + 4 * ks) ^ (ll & 7)) << 3)];
#pragma unroll
            for (int ct = 0; ct < 2; ++ct) {
                const int rem = (2 * wv + ct + ky) * 18 + zp;
                const bf16x8 bfr = *(const bf16x8*)&T[rem * 64 + (((lg + 4 * ks) ^ zs) << 3)];
#pragma unroll
                for (int rt = 0; rt < 4; ++rt)
                    acc[rt][ct] = __builtin_amdgcn_mfma_f32_16x16x32_bf16(af[rt], bfr, acc[rt][ct], 0, 0, 0);
            }
        }
        __syncthreads();
    }
    float* ob = out + (size_t)b * 4194304 + wsp * 4096 + x * 256;
#pragma unroll
    for (int rt = 0; rt < 4; ++rt) {
        const int co0 = rt * 16 + 4 * lg;
#pragma unroll
        for (int ct = 0; ct < 2; ++ct) {
            const int base = (2 * wv + ct) * 16 + ll;
#pragma unroll
            for (int r = 0; r < 4; ++r)
                ob[(size_t)(co0 + r) * 65536 + base] = acc[rt][ct][r];
        }
    }
}

extern "C" void kernel_launch(void* const* d_in, const int* in_sizes, int n_in,
                              void* d_out, int out_size, void* d_ws, size_t ws_size,
                              hipStream_t stream) {
    const float* in  = (const float*)d_in[0];
    const float* ker = (const float*)d_in[1];
    float* out = (float*)d_out;
    if (ws_size >= (size_t)WS_NEEDED) {
        u16* wg = (u16*)d_ws;
        u16* s  = (u16*)((char*)d_ws + S_OFF_BYTES);
        wprep<<<dim3(162), dim3(256), 0, stream>>>(ker, wg);
        sprep<<<dim3(648), dim3(256), 0, stream>>>(in, s);
        conv4d_main<<<dim3(512), dim3(512), 0, stream>>>(wg, s, out);
    } else {
        conv4d_mfma<<<dim3(512), dim3(512), 0, stream>>>(in, ker, out);
    }
}

// Round 9
// 100.909 us; speedup vs baseline: 1.2558x; 1.2558x over previous
//
#include <hip/hip_runtime.h>

// Conv4d implicit GEMM, v9 = v6 + counted-vmcnt pipeline (T3/T4).
// wprep: weights f32 -> bf16 in MFMA-fragment order Wg[off][rt][ks][lane][8].
// sprep: input f32 -> bf16 half-slabs S[(b,w',x')][ks][rem=y'*18+z'][32 ci],
//        granule-swizzled: granule g of row rem at g ^ ((rem>>1)&3) (2-way max on read).
// main:  block = (b,w,x), 256 thr / 4 waves, wave owns y-tiles 4wv..4wv+3 (4 ct x 4 rt,
//        16x16x32 MFMA — the verified v6 inner loop, VGPR 100, zero bank conflicts).
//        18 ticks (9 kwx x 2 ks); 3-slot half-slab ring (62KB, 2 blocks/CU): stage p+2
//        at tick top; tick ends with s_waitcnt vmcnt(6) + sched_barrier + RAW s_barrier
//        (no vmcnt(0) drain: slab p+2's 6 loads stay in flight across the barrier).
//        Staging = uniform 6 global_load_lds per wave (per-wave 324-unit chunk,
//        lane-linear dest; 6th load exec-masked to l<4) so vmcnt(6) exactly means
//        "slab p+1 complete" (in-order vmcnt retirement).

typedef __attribute__((ext_vector_type(8))) short bf16x8;
typedef __attribute__((ext_vector_type(4))) float f32x4;
typedef __attribute__((ext_vector_type(8))) unsigned short ushort8;
typedef unsigned short u16;
typedef unsigned int u32;

#define S_OFF_BYTES 663552u          // Wg = 81*4096 u16
#define WS_NEEDED   27537408u        // + 648 slabs * 41472 B

__device__ __forceinline__ u16 f2bf(float f) {
    u32 u = __float_as_uint(f);
    u += 0x7FFFu + ((u >> 16) & 1u);   // RNE
    return (u16)(u >> 16);
}

// ---------------- pre-pass 1: weights ----------------
__global__ __launch_bounds__(256) void wprep(const float* __restrict__ ker, u16* __restrict__ wg) {
    const int g = blockIdx.x * 256 + threadIdx.x;      // 0..41471
    const int l = g & 63, ks = (g >> 6) & 1, rt = (g >> 7) & 3, off = g >> 9;
    const int co  = rt * 16 + (l & 15);
    const int ci0 = ks * 32 + (l >> 4) * 8;
    const float* p = ker + (size_t)off * 4096 + co;
    ushort8 v;
#pragma unroll
    for (int e = 0; e < 8; ++e) v[e] = f2bf(p[(size_t)(ci0 + e) * 64]);
    *(ushort8*)(wg + (size_t)g * 8) = v;
}

// ---------------- pre-pass 2: input half-slabs (granule-swizzled) ----------------
__global__ __launch_bounds__(256) void sprep(const float* __restrict__ in, u16* __restrict__ s) {
    __shared__ u16 L[64 * 330];                        // [ci][rem padded]
    const int blk = blockIdx.x;                        // 648 = 2*18*18
    const int b = blk / 324, wx = blk - b * 324;
    const float* src = in + (size_t)b * 6718464 + (wx / 18) * 5832 + (wx % 18) * 324;
    const int t = threadIdx.x;
    for (int i = t; i < 5184; i += 256) {              // 64 ci * 81 float4
        const int ci = i / 81, j = i - ci * 81;
        float4 v = *(const float4*)(src + (size_t)ci * 104976 + j * 4);
        u32* q = (u32*)&L[ci * 330 + j * 4];
        q[0] = f2bf(v.x) | ((u32)f2bf(v.y) << 16);
        q[1] = f2bf(v.z) | ((u32)f2bf(v.w) << 16);
    }
    __syncthreads();
    u16* dst = s + (size_t)blk * 20736;                // [ks][rem][32 swizzled]
    for (int i = t; i < 2592; i += 256) {              // 2 ks * 324 rem * 4 granules
        const int ks = i / 1296, r4 = i - ks * 1296;
        const int rem = r4 >> 2, g = r4 & 3;
        ushort8 v;
#pragma unroll
        for (int e = 0; e < 8; ++e) v[e] = L[(ks * 32 + g * 8 + e) * 330 + rem];
        const int gp = g ^ ((rem >> 1) & 3);           // involution granule swizzle
        *(ushort8*)(dst + ks * 10368 + rem * 32 + gp * 8) = v;
    }
}

// ---------------- main ----------------
__global__ __launch_bounds__(256, 2)
void conv4d_main(const u16* __restrict__ wg, const u16* __restrict__ s, float* __restrict__ out) {
    __shared__ u16 R[3][324 * 32];                     // 3-slot half-slab ring, 62208 B

    // bijective XCD swizzle (512 % 8 == 0)
    const int bid = blockIdx.x;
    const int bs  = (bid & 7) * 64 + (bid >> 3);
    const int b   = bs >> 8;
    const int w   = (bs >> 4) & 15;
    const int x   = bs & 15;

    const int t  = threadIdx.x, wv = t >> 6, l = t & 63;
    const int lg = l >> 4, ll = l & 15;

    f32x4 acc[4][4];
#pragma unroll
    for (int i = 0; i < 4; ++i)
#pragma unroll
        for (int j = 0; j < 4; ++j) acc[i][j] = (f32x4){0.f, 0.f, 0.f, 0.f};

    const u16* sb = s + (size_t)(b * 324 + w * 18 + x) * 20736;

    // half-slab h: kwx = h>>1, ks-half = h&1. Uniform 6 global_load_lds per wave:
    // wave wv owns units [324*wv, 324*(wv+1)) of 16B; dest = uniform + l*16.
#define STAGE_U(h, slot)                                                                 \
    do {                                                                                 \
        const int kwx_ = (h) >> 1, ks_ = (h) & 1;                                        \
        const int kw_ = kwx_ / 3, kx_ = kwx_ - kw_ * 3;                                  \
        const u16* src_ = sb + (size_t)(kw_ * 18 + kx_) * 20736 + ks_ * 10368;           \
        const int base_ = wv * 324;                                                      \
        _Pragma("unroll")                                                                \
        for (int k_ = 0; k_ < 5; ++k_) {                                                 \
            const int i_ = base_ + k_ * 64 + l;                                          \
            __builtin_amdgcn_global_load_lds(                                            \
                (const __attribute__((address_space(1))) u32*)(src_ + (size_t)i_ * 8),   \
                (__attribute__((address_space(3))) u32*)&R[slot][i_ * 8], 16, 0, 0);     \
        }                                                                                \
        if (l < 4) {                                                                     \
            const int i_ = base_ + 320 + l;                                              \
            __builtin_amdgcn_global_load_lds(                                            \
                (const __attribute__((address_space(1))) u32*)(src_ + (size_t)i_ * 8),   \
                (__attribute__((address_space(3))) u32*)&R[slot][i_ * 8], 16, 0, 0);     \
        }                                                                                \
    } while (0)

    STAGE_U(0, 0);
    STAGE_U(1, 1);
    asm volatile("s_waitcnt vmcnt(6)" ::: "memory");   // slab 0 done; slab 1 in flight
    __builtin_amdgcn_sched_barrier(0);
    __builtin_amdgcn_s_barrier();

    for (int p = 0; p < 18; ++p) {
        if (p + 2 < 18) STAGE_U(p + 2, (p + 2) % 3);   // prefetch 2 ahead

        const int kwx = p >> 1, ks = p & 1;
        const u16* wo = wg + (size_t)(kwx * 9) * 4096 + ks * 512;
        const u16* Tb = R[p % 3];

        bf16x8 a[4][4];                                // 4-deep A ring (3 subs ahead)
#pragma unroll
        for (int i = 0; i < 3; ++i)
#pragma unroll
            for (int rt = 0; rt < 4; ++rt)
                a[i][rt] = *(const bf16x8*)(wo + (size_t)i * 4096 + (size_t)rt * 1024 + l * 8);

#pragma unroll
        for (int sub = 0; sub < 9; ++sub) {            // full unroll: ring idx static
            if (sub + 3 < 9) {
                const u16* wn = wo + (size_t)(sub + 3) * 4096;
#pragma unroll
                for (int rt = 0; rt < 4; ++rt)
                    a[(sub + 3) & 3][rt] = *(const bf16x8*)(wn + (size_t)rt * 1024 + l * 8);
            }
            const int ky = sub / 3, kz = sub - ky * 3;
            bf16x8 bfr[4];
#pragma unroll
            for (int ct = 0; ct < 4; ++ct) {
                const int rem = (4 * wv + ct + ky) * 18 + ll + kz;
                bfr[ct] = *(const bf16x8*)&Tb[rem * 32 + ((lg ^ ((rem >> 1) & 3)) << 3)];
            }
            __builtin_amdgcn_s_setprio(1);
#pragma unroll
            for (int ct = 0; ct < 4; ++ct)
#pragma unroll
                for (int rt = 0; rt < 4; ++rt)
                    acc[rt][ct] = __builtin_amdgcn_mfma_f32_16x16x32_bf16(
                        a[sub & 3][rt], bfr[ct], acc[rt][ct], 0, 0, 0);
            __builtin_amdgcn_s_setprio(0);
        }

        if (p < 17) {
            // counted wait: <=6 outstanding == only slab p+2's stage in flight
            // => slab p+1 (read next tick by all waves) is complete. No full drain.
            if (p < 16) asm volatile("s_waitcnt vmcnt(6)" ::: "memory");
            else        asm volatile("s_waitcnt vmcnt(0)" ::: "memory");
            __builtin_amdgcn_sched_barrier(0);
            __builtin_amdgcn_s_barrier();
        }
    }
#undef STAGE_U

    float* ob = out + (size_t)b * 4194304 + (size_t)w * 4096 + (size_t)x * 256;
#pragma unroll
    for (int rt = 0; rt < 4; ++rt) {
        const int co0 = rt * 16 + 4 * lg;
#pragma unroll
        for (int ct = 0; ct < 4; ++ct) {
            const int base = (4 * wv + ct) * 16 + ll;
#pragma unroll
            for (int r = 0; r < 4; ++r)
                ob[(size_t)(co0 + r) * 65536 + base] = acc[rt][ct][r];
        }
    }
}

// ---------------- fallback (round-1 kernel, used if ws too small) ----------------
__global__ __launch_bounds__(512, 2)
void conv4d_mfma(const float* __restrict__ in, const float* __restrict__ ker,
                 float* __restrict__ out) {
    __shared__ unsigned short T[18 * 18 * 64];
    __shared__ unsigned short Wt[2][64 * 64];
    const int bx = blockIdx.x;
    const int b = bx >> 8, wsp = (bx >> 4) & 15, x = bx & 15;
    const int t = threadIdx.x, wv = t >> 6, l = t & 63;
    const int lg = l >> 4, ll = l & 15;
    const float* inb = in + (size_t)b * 6718464 + wsp * 5832 + x * 324;
    f32x4 acc[4][2];
#pragma unroll
    for (int i = 0; i < 4; ++i)
#pragma unroll
        for (int j = 0; j < 2; ++j) acc[i][j] = (f32x4){0.f, 0.f, 0.f, 0.f};
#pragma unroll
    for (int f0 = 0; f0 < 4096; f0 += 512) {
        const int f = f0 + t, ci = f >> 6, co = f & 63;
        Wt[0][co * 64 + ((((ci >> 3) ^ (co & 7)) << 3) | (ci & 7))] = f2bf(ker[f]);
    }
    for (int off = 0; off < 81; ++off) {
        const int sub = off % 9;
        if (sub == 0) {
            const int kw = off / 27, kx = (off / 9) % 3;
            const float* p = inb + kw * 5832 + kx * 324;
            for (int f = t; f < 18 * 18 * 64; f += 512) {
                const int ci = f / 324, rem = f - ci * 324, zp = rem % 18;
                T[rem * 64 + ((((ci >> 3) ^ (zp & 7)) << 3) | (ci & 7))] =
                    f2bf(p[(size_t)ci * 104976 + rem]);
            }
        }
        if (off + 1 < 81) {
            const float* p = ker + (off + 1) * 4096;
            unsigned short* wb = Wt[(off + 1) & 1];
#pragma unroll
            for (int f0 = 0; f0 < 4096; f0 += 512) {
                const int f = f0 + t, ci = f >> 6, co = f & 63;
                wb[co * 64 + ((((ci >> 3) ^ (co & 7)) << 3) | (ci & 7))] = f2bf(p[f]);
            }
        }
        if (sub == 0) __syncthreads();
        const int ky = sub / 3, kz = sub - ky * 3;
        const int zp = ll + kz, zs = zp & 7;
#pragma unroll
        for (int ks = 0; ks < 2; ++ks) {
            bf16x8 af[4];
#pragma unroll
            for (int rt = 0; rt < 4; ++rt)
                af[rt] = *(const bf16x8*)&Wt[off & 1][(rt * 16 + ll) * 64 + (((lg + 4 * ks) ^ (ll & 7)) << 3)];
#pragma unroll
            for (int ct = 0; ct < 2; ++ct) {
                const int rem = (2 * wv + ct + ky) * 18 + zp;
                const bf16x8 bfr = *(const bf16x8*)&T[rem * 64 + (((lg + 4 * ks) ^ zs) << 3)];
#pragma unroll
                for (int rt = 0; rt < 4; ++rt)
                    acc[rt][ct] = __builtin_amdgcn_mfma_f32_16x16x32_bf16(af[rt], bfr, acc[rt][ct], 0, 0, 0);
            }
        }
        __syncthreads();
    }
    float* ob = out + (size_t)b * 4194304 + wsp * 4096 + x * 256;
#pragma unroll
    for (int rt = 0; rt < 4; ++rt) {
        const int co0 = rt * 16 + 4 * lg;
#pragma unroll
        for (int ct = 0; ct < 2; ++ct) {
            const int base = (2 * wv + ct) * 16 + ll;
#pragma unroll
            for (int r = 0; r < 4; ++r)
                ob[(size_t)(co0 + r) * 65536 + base] = acc[rt][ct][r];
        }
    }
}

extern "C" void kernel_launch(void* const* d_in, const int* in_sizes, int n_in,
                              void* d_out, int out_size, void* d_ws, size_t ws_size,
                              hipStream_t stream) {
    const float* in  = (const float*)d_in[0];
    const float* ker = (const float*)d_in[1];
    float* out = (float*)d_out;
    if (ws_size >= (size_t)WS_NEEDED) {
        u16* wg = (u16*)d_ws;
        u16* s  = (u16*)((char*)d_ws + S_OFF_BYTES);
        wprep<<<dim3(162), dim3(256), 0, stream>>>(ker, wg);
        sprep<<<dim3(648), dim3(256), 0, stream>>>(in, s);
        conv4d_main<<<dim3(512), dim3(256), 0, stream>>>(wg, s, out);
    } else {
        conv4d_mfma<<<dim3(512), dim3(512), 0, stream>>>(in, ker, out);
    }
}

// Round 10
// 92.433 us; speedup vs baseline: 1.3710x; 1.0917x over previous
//
#include <hip/hip_runtime.h>

// Conv4d implicit GEMM, v10 = v6 + kz-outer B-row reuse + cross-tick A-ring.
// wprep: weights f32 -> bf16 in MFMA-fragment order Wg[off][rt][ks][lane][8].
// sprep: input f32 -> bf16 half-slabs S[(b,w',x')][ks][rem=y'*18+z'][32 ci],
//        granule-swizzled: granule g of row rem at g ^ ((rem>>1)&3) (2-way max on read).
// main:  block = (b,w,x), 256 thr / 4 waves, wave owns y-tiles 4wv..4wv+3.
//        18 ticks (9 kwx x 2 ks), 3-slot half-slab ring staged 2 ahead.
//        Inner 9 subs in kz-major order j=(kz*3+ky), sub=ky*3+kz:
//          - B: per kz load 6 rows (4wv+0..5) once into 2-bank bb[][6];
//            fragment for (ct,ky) = bb[bank(kz)][ct+ky]  -> 18 ds_reads/tick (was 36),
//            issued a full kz-group ahead of consumption.
//          - A: depth-3 ring over the flattened 162-step stream (slot = j%3, static),
//            prefetch distance 3 -> tick p+1's first subs load BEFORE the barrier,
//            no per-tick cold start.
//        Plain __syncthreads() per tick (counted-vmcnt proven ineffective when A
//        streams through VGPR loads: compiler A-waits force-retire older stage ops).

typedef __attribute__((ext_vector_type(8))) short bf16x8;
typedef __attribute__((ext_vector_type(4))) float f32x4;
typedef __attribute__((ext_vector_type(8))) unsigned short ushort8;
typedef unsigned short u16;
typedef unsigned int u32;

#define S_OFF_BYTES 663552u          // Wg = 81*4096 u16
#define WS_NEEDED   27537408u        // + 648 slabs * 41472 B

__device__ __forceinline__ u16 f2bf(float f) {
    u32 u = __float_as_uint(f);
    u += 0x7FFFu + ((u >> 16) & 1u);   // RNE
    return (u16)(u >> 16);
}

// ---------------- pre-pass 1: weights ----------------
__global__ __launch_bounds__(256) void wprep(const float* __restrict__ ker, u16* __restrict__ wg) {
    const int g = blockIdx.x * 256 + threadIdx.x;      // 0..41471
    const int l = g & 63, ks = (g >> 6) & 1, rt = (g >> 7) & 3, off = g >> 9;
    const int co  = rt * 16 + (l & 15);
    const int ci0 = ks * 32 + (l >> 4) * 8;
    const float* p = ker + (size_t)off * 4096 + co;
    ushort8 v;
#pragma unroll
    for (int e = 0; e < 8; ++e) v[e] = f2bf(p[(size_t)(ci0 + e) * 64]);
    *(ushort8*)(wg + (size_t)g * 8) = v;
}

// ---------------- pre-pass 2: input half-slabs (granule-swizzled) ----------------
__global__ __launch_bounds__(256) void sprep(const float* __restrict__ in, u16* __restrict__ s) {
    __shared__ u16 L[64 * 330];                        // [ci][rem padded]
    const int blk = blockIdx.x;                        // 648 = 2*18*18
    const int b = blk / 324, wx = blk - b * 324;
    const float* src = in + (size_t)b * 6718464 + (wx / 18) * 5832 + (wx % 18) * 324;
    const int t = threadIdx.x;
    for (int i = t; i < 5184; i += 256) {              // 64 ci * 81 float4
        const int ci = i / 81, j = i - ci * 81;
        float4 v = *(const float4*)(src + (size_t)ci * 104976 + j * 4);
        u32* q = (u32*)&L[ci * 330 + j * 4];
        q[0] = f2bf(v.x) | ((u32)f2bf(v.y) << 16);
        q[1] = f2bf(v.z) | ((u32)f2bf(v.w) << 16);
    }
    __syncthreads();
    u16* dst = s + (size_t)blk * 20736;                // [ks][rem][32 swizzled]
    for (int i = t; i < 2592; i += 256) {              // 2 ks * 324 rem * 4 granules
        const int ks = i / 1296, r4 = i - ks * 1296;
        const int rem = r4 >> 2, g = r4 & 3;
        ushort8 v;
#pragma unroll
        for (int e = 0; e < 8; ++e) v[e] = L[(ks * 32 + g * 8 + e) * 330 + rem];
        const int gp = g ^ ((rem >> 1) & 3);           // involution granule swizzle
        *(ushort8*)(dst + ks * 10368 + rem * 32 + gp * 8) = v;
    }
}

// ---------------- main ----------------
__global__ __launch_bounds__(256, 2)
void conv4d_main(const u16* __restrict__ wg, const u16* __restrict__ s, float* __restrict__ out) {
    __shared__ u16 R[3][324 * 32];                     // 3-slot half-slab ring, 62208 B

    // bijective XCD swizzle (512 % 8 == 0)
    const int bid = blockIdx.x;
    const int bs  = (bid & 7) * 64 + (bid >> 3);
    const int b   = bs >> 8;
    const int w   = (bs >> 4) & 15;
    const int x   = bs & 15;

    const int t  = threadIdx.x, wv = t >> 6, l = t & 63;
    const int lg = l >> 4, ll = l & 15;

    f32x4 acc[4][4];
#pragma unroll
    for (int i = 0; i < 4; ++i)
#pragma unroll
        for (int j = 0; j < 4; ++j) acc[i][j] = (f32x4){0.f, 0.f, 0.f, 0.f};

    const u16* sb = s + (size_t)(b * 324 + w * 18 + x) * 20736;

#define STAGE_U(h, slot)                                                                 \
    do {                                                                                 \
        const int kwx_ = (h) >> 1, ks_ = (h) & 1;                                        \
        const int kw_ = kwx_ / 3, kx_ = kwx_ - kw_ * 3;                                  \
        const u16* src_ = sb + (size_t)(kw_ * 18 + kx_) * 20736 + ks_ * 10368;           \
        const int base_ = wv * 324;                                                      \
        _Pragma("unroll")                                                                \
        for (int k_ = 0; k_ < 5; ++k_) {                                                 \
            const int i_ = base_ + k_ * 64 + l;                                          \
            __builtin_amdgcn_global_load_lds(                                            \
                (const __attribute__((address_space(1))) u32*)(src_ + (size_t)i_ * 8),   \
                (__attribute__((address_space(3))) u32*)&R[slot][i_ * 8], 16, 0, 0);     \
        }                                                                                \
        if (l < 4) {                                                                     \
            const int i_ = base_ + 320 + l;                                              \
            __builtin_amdgcn_global_load_lds(                                            \
                (const __attribute__((address_space(1))) u32*)(src_ + (size_t)i_ * 8),   \
                (__attribute__((address_space(3))) u32*)&R[slot][i_ * 8], 16, 0, 0);     \
        }                                                                                \
    } while (0)

    STAGE_U(0, 0);
    STAGE_U(1, 1);

    // prologue A-ring: stream steps u=0,1,2 == tick 0, j=0,1,2 -> subs 0,3,6 (ks=0)
    bf16x8 a[3][4];
#pragma unroll
    for (int i = 0; i < 3; ++i)
#pragma unroll
        for (int rt = 0; rt < 4; ++rt)
            a[i][rt] = *(const bf16x8*)(wg + (size_t)(i * 3) * 4096 + (size_t)rt * 1024 + l * 8);

    __syncthreads();

    bf16x8 bb[2][6];                                   // 2-bank 6-row B file

    for (int p = 0; p < 18; ++p) {
        if (p + 2 < 18) STAGE_U(p + 2, (p + 2) % 3);   // stage 2 ticks ahead

        const u16* Tb = R[p % 3];

        // load 6 B rows (4wv+0..5) at column ll+kz into bank
#define LOADB(bank, kz_)                                                             \
        do {                                                                         \
            _Pragma("unroll")                                                        \
            for (int q_ = 0; q_ < 6; ++q_) {                                         \
                const int rem_ = (4 * wv + q_) * 18 + ll + (kz_);                    \
                bb[bank][q_] = *(const bf16x8*)&Tb[rem_ * 32 +                       \
                                   ((lg ^ ((rem_ >> 1) & 3)) << 3)];                 \
            }                                                                        \
        } while (0)

#pragma unroll
        for (int j = 0; j < 9; ++j) {                  // kz = j/3, ky = j%3 (all static)
            const int ky = j % 3;
            if (j == 0) LOADB(0, 0);                   // kz0 -> bank0
            if (j == 1) LOADB(1, 1);                   // kz1 -> bank1 (shadowed)
            if (j == 3) LOADB(0, 2);                   // kz2 -> bank0 (bank free after j=2)
            const int bank = (j >= 3 && j < 6) ? 1 : 0;

            __builtin_amdgcn_s_setprio(1);
#pragma unroll
            for (int ct = 0; ct < 4; ++ct)
#pragma unroll
                for (int rt = 0; rt < 4; ++rt)
                    acc[rt][ct] = __builtin_amdgcn_mfma_f32_16x16x32_bf16(
                        a[j % 3][rt], bb[bank][ct + ky], acc[rt][ct], 0, 0, 0);
            __builtin_amdgcn_s_setprio(0);

            // A-ring prefetch: stream step u+3 (crosses the tick boundary at j>=6)
            {
                const int pj = (j + 3 < 9) ? p : p + 1;
                const int jj = (j + 3) % 9;
                if (pj < 18) {
                    const int sub2 = (jj % 3) * 3 + jj / 3;     // ky'*3 + kz'
                    const u16* wn = wg + (size_t)((pj >> 1) * 9 + sub2) * 4096 + (pj & 1) * 512;
#pragma unroll
                    for (int rt = 0; rt < 4; ++rt)
                        a[j % 3][rt] = *(const bf16x8*)(wn + (size_t)rt * 1024 + l * 8);
                }
            }
        }
#undef LOADB
        __syncthreads();                               // drains stage + A prefetches
    }
#undef STAGE_U

    float* ob = out + (size_t)b * 4194304 + (size_t)w * 4096 + (size_t)x * 256;
#pragma unroll
    for (int rt = 0; rt < 4; ++rt) {
        const int co0 = rt * 16 + 4 * lg;
#pragma unroll
        for (int ct = 0; ct < 4; ++ct) {
            const int base = (4 * wv + ct) * 16 + ll;
#pragma unroll
            for (int r = 0; r < 4; ++r)
                ob[(size_t)(co0 + r) * 65536 + base] = acc[rt][ct][r];
        }
    }
}

// ---------------- fallback (round-1 kernel, used if ws too small) ----------------
__global__ __launch_bounds__(512, 2)
void conv4d_mfma(const float* __restrict__ in, const float* __restrict__ ker,
                 float* __restrict__ out) {
    __shared__ unsigned short T[18 * 18 * 64];
    __shared__ unsigned short Wt[2][64 * 64];
    const int bx = blockIdx.x;
    const int b = bx >> 8, wsp = (bx >> 4) & 15, x = bx & 15;
    const int t = threadIdx.x, wv = t >> 6, l = t & 63;
    const int lg = l >> 4, ll = l & 15;
    const float* inb = in + (size_t)b * 6718464 + wsp * 5832 + x * 324;
    f32x4 acc[4][2];
#pragma unroll
    for (int i = 0; i < 4; ++i)
#pragma unroll
        for (int j = 0; j < 2; ++j) acc[i][j] = (f32x4){0.f, 0.f, 0.f, 0.f};
#pragma unroll
    for (int f0 = 0; f0 < 4096; f0 += 512) {
        const int f = f0 + t, ci = f >> 6, co = f & 63;
        Wt[0][co * 64 + ((((ci >> 3) ^ (co & 7)) << 3) | (ci & 7))] = f2bf(ker[f]);
    }
    for (int off = 0; off < 81; ++off) {
        const int sub = off % 9;
        if (sub == 0) {
            const int kw = off / 27, kx = (off / 9) % 3;
            const float* p = inb + kw * 5832 + kx * 324;
            for (int f = t; f < 18 * 18 * 64; f += 512) {
                const int ci = f / 324, rem = f - ci * 324, zp = rem % 18;
                T[rem * 64 + ((((ci >> 3) ^ (zp & 7)) << 3) | (ci & 7))] =
                    f2bf(p[(size_t)ci * 104976 + rem]);
            }
        }
        if (off + 1 < 81) {
            const float* p = ker + (off + 1) * 4096;
            unsigned short* wb = Wt[(off + 1) & 1];
#pragma unroll
            for (int f0 = 0; f0 < 4096; f0 += 512) {
                const int f = f0 + t, ci = f >> 6, co = f & 63;
                wb[co * 64 + ((((ci >> 3) ^ (co & 7)) << 3) | (ci & 7))] = f2bf(p[f]);
            }
        }
        if (sub == 0) __syncthreads();
        const int ky = sub / 3, kz = sub - ky * 3;
        const int zp = ll + kz, zs = zp & 7;
#pragma unroll
        for (int ks = 0; ks < 2; ++ks) {
            bf16x8 af[4];
#pragma unroll
            for (int rt = 0; rt < 4; ++rt)
                af[rt] = *(const bf16x8*)&Wt[off & 1][(rt * 16 + ll) * 64 + (((lg + 4 * ks) ^ (ll & 7)) << 3)];
#pragma unroll
            for (int ct = 0; ct < 2; ++ct) {
                const int rem = (2 * wv + ct + ky) * 18 + zp;
                const bf16x8 bfr = *(const bf16x8*)&T[rem * 64 + (((lg + 4 * ks) ^ zs) << 3)];
#pragma unroll
                for (int rt = 0; rt < 4; ++rt)
                    acc[rt][ct] = __builtin_amdgcn_mfma_f32_16x16x32_bf16(af[rt], bfr, acc[rt][ct], 0, 0, 0);
            }
        }
        __syncthreads();
    }
    float* ob = out + (size_t)b * 4194304 + wsp * 4096 + x * 256;
#pragma unroll
    for (int rt = 0; rt < 4; ++rt) {
        const int co0 = rt * 16 + 4 * lg;
#pragma unroll
        for (int ct = 0; ct < 2; ++ct) {
            const int base = (2 * wv + ct) * 16 + ll;
#pragma unroll
            for (int r = 0; r < 4; ++r)
                ob[(size_t)(co0 + r) * 65536 + base] = acc[rt][ct][r];
        }
    }
}

extern "C" void kernel_launch(void* const* d_in, const int* in_sizes, int n_in,
                              void* d_out, int out_size, void* d_ws, size_t ws_size,
                              hipStream_t stream) {
    const float* in  = (const float*)d_in[0];
    const float* ker = (const float*)d_in[1];
    float* out = (float*)d_out;
    if (ws_size >= (size_t)WS_NEEDED) {
        u16* wg = (u16*)d_ws;
        u16* s  = (u16*)((char*)d_ws + S_OFF_BYTES);
        wprep<<<dim3(162), dim3(256), 0, stream>>>(ker, wg);
        sprep<<<dim3(648), dim3(256), 0, stream>>>(in, s);
        conv4d_main<<<dim3(512), dim3(256), 0, stream>>>(wg, s, out);
    } else {
        conv4d_mfma<<<dim3(512), dim3(512), 0, stream>>>(in, ker, out);
    }
}